// Round 8
// baseline (350.090 us; speedup 1.0000x reference)
//
#include <hip/hip_runtime.h>

// MPRelativeSelfMultiheadAttn on gfx950.
// hypernet+casts (fused, coalesced weight dot8) -> merged fp16 MFMA GEMM
// (qkv + pos in ONE 640-block launch, XCD-chunked swizzle; global_load_lds
// with XOR-swizzled gather => conflict-free ds_read_b128) -> V transpose ->
// flash attention QBLK=128 (8 waves/512 thr, K/V/R tiles shared by 2x Q-rows,
// rel_shift fused, online softmax, writes attn_h h16 directly) ->
// out GEMM (64x128 tiles, 256 blocks = 1/CU).
// XOR swizzle: LDS(row, g) = global(row, g ^ (row&7)), granule = 16B.
// Fragment read granule = (kc*4+quad) ^ (t16&7): all 32 banks per 8-lane group.

typedef _Float16 h16;
typedef _Float16 h16x8 __attribute__((ext_vector_type(8)));
typedef _Float16 h16x4 __attribute__((ext_vector_type(4)));
typedef float f32x4 __attribute__((ext_vector_type(4)));

static __device__ __forceinline__ f32x4 mfma16(h16x8 a, h16x8 b, f32x4 c) {
  return __builtin_amdgcn_mfma_f32_16x16x32_f16(a, b, c, 0, 0, 0);
}
static __device__ __forceinline__ void gload16(const void* g, void* l) {
  __builtin_amdgcn_global_load_lds((const __attribute__((address_space(1))) void*)g,
                                   (__attribute__((address_space(3))) void*)l, 16, 0, 0);
}

// ---------------- hypernet + casts (fused, coalesced weight path) ----------------
__global__ __launch_bounds__(256) void hypernet_kernel(
    const float* __restrict__ fac,
    const float* __restrict__ w_in, const float* __restrict__ w_pos,
    const float* __restrict__ w_out, const float* __restrict__ b_in_w,
    const float* __restrict__ b_pos_w, const float* __restrict__ b_out_w,
    const float* __restrict__ rw_w, const float* __restrict__ rr_w,
    h16* __restrict__ Win, h16* __restrict__ Wpos, h16* __restrict__ Wout,
    float* __restrict__ bin, float* __restrict__ bpos, float* __restrict__ bout,
    float* __restrict__ rw, float* __restrict__ rr, h16* __restrict__ rb,
    const float* __restrict__ input, h16* __restrict__ in_h,
    const float* __restrict__ pos, h16* __restrict__ pos_h)
{
  float f0=fac[0],f1=fac[1],f2=fac[2],f3=fac[3],f4=fac[4],f5=fac[5],f6=fac[6],f7=fac[7];
#define DOT8(p) ((p)[0]*f0+(p)[1]*f1+(p)[2]*f2+(p)[3]*f3+(p)[4]*f4+(p)[5]*f5+(p)[6]*f6+(p)[7]*f7)
  // ---- weight path: blocks [0, 5120), 256 rows per wave ----
  if (blockIdx.x < 5120) {
    const int lane = threadIdx.x & 63;
    const int gw = blockIdx.x * 4 + (threadIdx.x >> 6);   // global wave id
    size_t rowBase = (size_t)gw * 256;
    const float* srcp; h16* dstp; size_t lr;
    if (rowBase < 3145728)      { srcp = w_in;  dstp = Win;  lr = rowBase; }
    else if (rowBase < 4194304) { srcp = w_pos; dstp = Wpos; lr = rowBase - 3145728; }
    else                        { srcp = w_out; dstp = Wout; lr = rowBase - 4194304; }
    const f32x4* p = reinterpret_cast<const f32x4*>(srcp) + lr*2;
    const int pi = (lane < 32) ? (lane << 1) : (((lane - 32) << 1) | 1);
    const float fa = (lane < 32) ? f0 : f4;
    const float fb = (lane < 32) ? f1 : f5;
    const float fc = (lane < 32) ? f2 : f6;
    const float fd = (lane < 32) ? f3 : f7;
    f32x4 v[8];
#pragma unroll
    for (int u = 0; u < 8; ++u) v[u] = p[(size_t)u*64 + pi];   // coalesced 1KB each
    float full[8];
#pragma unroll
    for (int u = 0; u < 8; ++u) {
      float part = v[u].x*fa + v[u].y*fb + v[u].z*fc + v[u].w*fd;
      full[u] = part + __shfl_xor(part, 32, 64);
    }
    if (lane < 32) {
#pragma unroll
      for (int u = 0; u < 8; ++u)
        dstp[lr + u*32 + lane] = (h16)full[u];
    }
    return;
  }
  int idx = (blockIdx.x - 5120) * 256 + threadIdx.x;
  // ---- tiny sections (1 output per thread) ----
  if (idx < 3072) { bin[idx]  = DOT8(b_in_w  + (size_t)idx*8); return; }
  idx -= 3072;
  if (idx < 1024) { bpos[idx] = DOT8(b_pos_w + (size_t)idx*8); return; }
  idx -= 1024;
  if (idx < 1024) { bout[idx] = DOT8(b_out_w + (size_t)idx*8); return; }
  idx -= 1024;
  if (idx < 1024) { rw[idx]   = DOT8(rw_w    + (size_t)idx*8); return; }
  idx -= 1024;
  if (idx < 1024) { rr[idx]   = DOT8(rr_w    + (size_t)idx*8); return; }
  idx -= 1024;
  if (idx < 2048) { rb[(((size_t)(idx >> 6)) << 17) + 2047*64 + (idx & 63)] = (h16)0.f; return; }
  idx -= 2048;
  // ---- casts: 2 float4 per thread -> one h16x8 store ----
  if (idx < 262144) {   // input: 524288 float4 total
    const float4* ip = reinterpret_cast<const float4*>(input) + (size_t)idx*2;
    float4 a = ip[0], b = ip[1];
    h16x8 o = { (h16)a.x, (h16)a.y, (h16)a.z, (h16)a.w,
                (h16)b.x, (h16)b.y, (h16)b.z, (h16)b.w };
    reinterpret_cast<h16x8*>(in_h)[idx] = o;
    return;
  }
  idx -= 262144;
  if (idx < 524032) {   // pos: 1048064 float4 total
    const float4* pp = reinterpret_cast<const float4*>(pos) + (size_t)idx*2;
    float4 a = pp[0], b = pp[1];
    h16x8 o = { (h16)a.x, (h16)a.y, (h16)a.z, (h16)a.w,
                (h16)b.x, (h16)b.y, (h16)b.z, (h16)b.w };
    reinterpret_cast<h16x8*>(pos_h)[idx] = o;
  }
#undef DOT8
}

// ---------------- merged GEMM: mode0 qkv (24x16) + mode1 pos (8x32), 640 blocks ----------------
__global__ __launch_bounds__(256) void gemm01_kernel(
    const h16* __restrict__ A0, const h16* __restrict__ B0, const float* __restrict__ bias0,
    const h16* __restrict__ A1, const h16* __restrict__ B1, const float* __restrict__ bias1,
    const float* __restrict__ rwv, const float* __restrict__ rrv,
    h16* __restrict__ o0, h16* __restrict__ o1,
    h16* __restrict__ o2, h16* __restrict__ o3, h16* __restrict__ r_out)
{
  __shared__ __align__(16) h16 a_sm[128*64];
  __shared__ __align__(16) h16 b_sm[128*64];
  // XCD swizzle: 80 consecutive logical blocks per XCD
  const int bx = blockIdx.x;
  const int swz = (bx & 7) * 80 + (bx >> 3);
  int mode, bxx, byy;
  if (swz < 384) { mode = 0; bxx = swz % 24; byy = swz / 24; }
  else           { mode = 1; int b = swz - 384; bxx = b & 7; byy = b >> 3; }
  const h16* __restrict__ A  = mode ? A1 : A0;
  const h16* __restrict__ Bw = mode ? B1 : B0;
  const float* __restrict__ bias = mode ? bias1 : bias0;
  const int M = mode ? 4094 : 2048;
  const int K = 1024;

  const int tid = threadIdx.x, lane = tid & 63, wave = tid >> 6;
  const int quad = lane >> 4, t16 = lane & 15;
  const int wm = wave >> 1, wn = wave & 1;
  const int m0 = byy * 128, n0 = bxx * 128;
  const int lrow = lane >> 3, lgran = lane & 7;
  const int gsw = (lgran ^ lrow) * 8;          // swizzled source col offset (h16)
  const int xg0 = (quad ^ (t16 & 7)) * 8;      // fragment granule, kc=0
  const int xg1 = xg0 ^ 32;                    // kc=1

  f32x4 acc[4][4];
#pragma unroll
  for (int i = 0; i < 4; ++i)
#pragma unroll
    for (int j = 0; j < 4; ++j) acc[i][j] = (f32x4){0.f,0.f,0.f,0.f};

  for (int k0 = 0; k0 < K; k0 += 64) {
    __syncthreads();
#pragma unroll
    for (int s = 0; s < 4; ++s) {
      int rbase = wave*32 + s*8;
      gload16(A  + (size_t)(m0 + rbase + lrow)*K + k0 + gsw, a_sm + rbase*64);
      gload16(Bw + (size_t)(n0 + rbase + lrow)*K + k0 + gsw, b_sm + rbase*64);
    }
    __syncthreads();
#pragma unroll
    for (int kc = 0; kc < 2; ++kc) {
      const int xg = kc ? xg1 : xg0;
      h16x8 af[4], bfr[4];
#pragma unroll
      for (int i = 0; i < 4; ++i) {
        af[i]  = *reinterpret_cast<const h16x8*>(a_sm + (wm*64 + i*16 + t16)*64 + xg);
        bfr[i] = *reinterpret_cast<const h16x8*>(b_sm + (wn*64 + i*16 + t16)*64 + xg);
      }
#pragma unroll
      for (int i = 0; i < 4; ++i)
#pragma unroll
        for (int j = 0; j < 4; ++j)
          acc[i][j] = mfma16(af[i], bfr[j], acc[i][j]);
    }
  }

  // epilogue: C/D layout row=(lane>>4)*4+reg, col=lane&15
#pragma unroll
  for (int i = 0; i < 4; ++i) {
    int mb = m0 + wm*64 + i*16 + quad*4;
#pragma unroll
    for (int j = 0; j < 4; ++j) {
      int n = n0 + wn*64 + j*16 + t16;
      float bv = bias[n];
      if (mode == 0) {
        int nn = n & 1023, sec = n >> 10, hh = nn >> 6, d = nn & 63;
        float rwb = rwv[nn], rrb = rrv[nn];
#pragma unroll
        for (int r = 0; r < 4; ++r) {
          int m = mb + r, t = m >> 1, b = m & 1;
          size_t off = ((size_t)((b << 4) + hh) << 16) + (t << 6) + d;
          float v = acc[i][j][r] + bv;
          if (sec == 0)      { o0[off] = (h16)(v + rwb); o1[off] = (h16)(v + rrb); }
          else if (sec == 1) { o2[off] = (h16)v; }
          else               { o3[off] = (h16)v; }
        }
      } else {
        int hh = n >> 6, d = n & 63;
#pragma unroll
        for (int r = 0; r < 4; ++r) {
          int m = mb + r;
          if (m < M) {
            int rel = m >> 1, b = m & 1;
            r_out[(((size_t)((b << 4) + hh)) << 17) + (rel << 6) + d] = (h16)(acc[i][j][r] + bv);
          }
        }
      }
    }
  }
}

// ---------------- out GEMM: 64x128 tiles, 256 blocks (1/CU) ----------------
__global__ __launch_bounds__(256) void gemm2_kernel(
    const h16* __restrict__ A, const h16* __restrict__ Bw,
    const float* __restrict__ bias, float* __restrict__ Cout)
{
  __shared__ __align__(16) h16 a_sm[64*64];
  __shared__ __align__(16) h16 b_sm[128*64];
  const int tid = threadIdx.x, lane = tid & 63, wave = tid >> 6;
  const int quad = lane >> 4, t16 = lane & 15;
  const int wm = wave >> 1, wn = wave & 1;
  const int m0 = blockIdx.y * 64, n0 = blockIdx.x * 128;
  const int lrow = lane >> 3, lgran = lane & 7;
  const int gsw = (lgran ^ lrow) * 8;
  const int xg0 = (quad ^ (t16 & 7)) * 8;
  const int xg1 = xg0 ^ 32;
  const int K = 1024, N = 1024;

  f32x4 acc[2][4];
#pragma unroll
  for (int i = 0; i < 2; ++i)
#pragma unroll
    for (int j = 0; j < 4; ++j) acc[i][j] = (f32x4){0.f,0.f,0.f,0.f};

  for (int k0 = 0; k0 < K; k0 += 64) {
    __syncthreads();
#pragma unroll
    for (int s = 0; s < 2; ++s) {   // A: 64 rows, 16/wave
      int rbase = wave*16 + s*8;
      gload16(A + (size_t)(m0 + rbase + lrow)*K + k0 + gsw, a_sm + rbase*64);
    }
#pragma unroll
    for (int s = 0; s < 4; ++s) {   // B: 128 rows, 32/wave
      int rbase = wave*32 + s*8;
      gload16(Bw + (size_t)(n0 + rbase + lrow)*K + k0 + gsw, b_sm + rbase*64);
    }
    __syncthreads();
#pragma unroll
    for (int kc = 0; kc < 2; ++kc) {
      const int xg = kc ? xg1 : xg0;
      h16x8 af[2], bfr[4];
#pragma unroll
      for (int i = 0; i < 2; ++i)
        af[i]  = *reinterpret_cast<const h16x8*>(a_sm + (wm*32 + i*16 + t16)*64 + xg);
#pragma unroll
      for (int j = 0; j < 4; ++j)
        bfr[j] = *reinterpret_cast<const h16x8*>(b_sm + (wn*64 + j*16 + t16)*64 + xg);
#pragma unroll
      for (int i = 0; i < 2; ++i)
#pragma unroll
        for (int j = 0; j < 4; ++j)
          acc[i][j] = mfma16(af[i], bfr[j], acc[i][j]);
    }
  }

#pragma unroll
  for (int i = 0; i < 2; ++i) {
    int mb = m0 + wm*32 + i*16 + quad*4;
#pragma unroll
    for (int j = 0; j < 4; ++j) {
      int n = n0 + wn*64 + j*16 + t16;
      float bv = bias[n];
#pragma unroll
      for (int r = 0; r < 4; ++r)
        Cout[(size_t)(mb + r)*N + n] = acc[i][j][r] + bv;
    }
  }
}

// ---------------- V transpose: vb [BH][T][64] -> vbt [BH][64][T] ----------------
__global__ __launch_bounds__(256) void transpose_v_kernel(
    const h16* __restrict__ vb, h16* __restrict__ vbt)
{
  __shared__ h16 tile[64*72];
  const int bh = blockIdx.y, t0 = blockIdx.x * 64;
  const int r = threadIdx.x >> 3, c = (threadIdx.x & 7) * 8;
  const h16* src = vb + ((size_t)bh << 16) + (size_t)(t0 + r)*64 + c;
  *reinterpret_cast<h16x8*>(tile + r*72 + c)        = *reinterpret_cast<const h16x8*>(src);
  *reinterpret_cast<h16x8*>(tile + (r + 32)*72 + c) = *reinterpret_cast<const h16x8*>(src + 32*64);
  __syncthreads();
  h16x8 o0, o1;
#pragma unroll
  for (int e = 0; e < 8; ++e) {
    o0[e] = tile[(c + e)*72 + r];
    o1[e] = tile[(c + e)*72 + r + 32];
  }
  h16* dst = vbt + ((size_t)bh << 16) + (size_t)r*1024 + t0 + c;
  *reinterpret_cast<h16x8*>(dst)            = o0;
  *reinterpret_cast<h16x8*>(dst + 32*1024)  = o1;
}

// ---------------- flash attention, QBLK=128 (8 waves), writes attn_h directly ----------------
// Per wave: 16 Q-rows (identical per-wave math to the 4-wave version).
// R staging: 192 rows from rel0 = j0-i0+896; wave window cb0 = 7-wave.
// In-window rel-shift offset (15 + jc - il) is wave-invariant (base cancels).
__global__ __launch_bounds__(512) void flash_kernel(
    const h16* __restrict__ qrw, const h16* __restrict__ qrr,
    const h16* __restrict__ kb, const h16* __restrict__ vbt,
    const h16* __restrict__ rb,
    h16* __restrict__ attn_h)
{
  __shared__ __align__(16) h16 k_sm[64*64];
  __shared__ __align__(16) h16 vt_sm[64*64];
  __shared__ __align__(16) h16 r_sm[192*64];   // reused as BD/P spill after barrier

  const int tid = threadIdx.x, lane = tid & 63, wave = tid >> 6;  // 0..7
  const int quad = lane >> 4, t16 = lane & 15;
  const int bh = blockIdx.y, i0 = blockIdx.x * 128;
  const size_t base  = (size_t)bh << 16;
  const size_t rbase = (size_t)bh << 17;
  const int iw = i0 + wave * 16;
  const int lrow = lane >> 3, lgran = lane & 7;
  const int gsw = (lgran ^ lrow) * 8;
  const int xg0 = (quad ^ (t16 & 7)) * 8;
  const int xg1 = xg0 ^ 32;

  h16x8 a_rw[2], a_rr[2];
  {
    const h16* p = qrw + base + (size_t)(iw + t16)*64 + quad*8;
    a_rw[0] = *reinterpret_cast<const h16x8*>(p);
    a_rw[1] = *reinterpret_cast<const h16x8*>(p + 32);
    const h16* p2 = qrr + base + (size_t)(iw + t16)*64 + quad*8;
    a_rr[0] = *reinterpret_cast<const h16x8*>(p2);
    a_rr[1] = *reinterpret_cast<const h16x8*>(p2 + 32);
  }

  f32x4 o_acc[4];
#pragma unroll
  for (int dc = 0; dc < 4; ++dc) o_acc[dc] = (f32x4){0.f,0.f,0.f,0.f};
  float m_run[4] = {-1e30f,-1e30f,-1e30f,-1e30f};
  float l_run[4] = {0.f,0.f,0.f,0.f};   // per-lane partial; reduced at end

  h16* bdw = r_sm + wave * (16*84);     // 8 x 1344 <= 12288 elems
  const int cb0 = 7 - wave;

  for (int j0 = 0; j0 < 1024; j0 += 64) {
    __syncthreads();
    { // swizzled staging: K,V 8 rows/wave; R 24 rows/wave (192 total)
      int row = wave*8;
      gload16(kb  + base + (size_t)(j0 + row + lrow)*64 + gsw, k_sm  + row*64);
      gload16(vbt + base + (size_t)(row + lrow)*1024 + j0 + gsw, vt_sm + row*64);
      const int rel0 = j0 - i0 + 896;
#pragma unroll
      for (int s = 0; s < 3; ++s) {
        int rr_ = wave*24 + s*8;
        gload16(rb + rbase + (size_t)(rel0 + rr_ + lrow)*64 + gsw, r_sm + rr_*64);
      }
    }
    __syncthreads();

    f32x4 s_ac[4];
#pragma unroll
    for (int c = 0; c < 4; ++c) {
      s_ac[c] = (f32x4){0.f,0.f,0.f,0.f};
      s_ac[c] = mfma16(a_rw[0], *reinterpret_cast<const h16x8*>(k_sm + (c*16 + t16)*64 + xg0), s_ac[c]);
      s_ac[c] = mfma16(a_rw[1], *reinterpret_cast<const h16x8*>(k_sm + (c*16 + t16)*64 + xg1), s_ac[c]);
    }
    f32x4 s_bd[5];
#pragma unroll
    for (int u = 0; u < 5; ++u) {
      s_bd[u] = (f32x4){0.f,0.f,0.f,0.f};
      s_bd[u] = mfma16(a_rr[0], *reinterpret_cast<const h16x8*>(r_sm + ((cb0+u)*16 + t16)*64 + xg0), s_bd[u]);
      s_bd[u] = mfma16(a_rr[1], *reinterpret_cast<const h16x8*>(r_sm + ((cb0+u)*16 + t16)*64 + xg1), s_bd[u]);
    }
    __syncthreads();  // r_sm reads done before spilling into it

    // BD spill (C-layout), stride 84
#pragma unroll
    for (int u = 0; u < 5; ++u)
#pragma unroll
      for (int r = 0; r < 4; ++r)
        bdw[(quad*4 + r)*84 + u*16 + t16] = (h16)s_bd[u][r];

    // combine with relative shift
    float sv[4][4];
#pragma unroll
    for (int c = 0; c < 4; ++c)
#pragma unroll
      for (int r = 0; r < 4; ++r) {
        int il = quad*4 + r;
        float bdv = (float)bdw[il*84 + c*16 + t16 + 15 - il];
        sv[c][r] = (s_ac[c][r] + bdv) * 0.125f;
      }

    // online softmax: shared row max (shfl), per-lane l partial
    float alpha[4];
#pragma unroll
    for (int r = 0; r < 4; ++r) {
      float v = fmaxf(fmaxf(sv[0][r], sv[1][r]), fmaxf(sv[2][r], sv[3][r]));
#pragma unroll
      for (int off = 1; off < 16; off <<= 1) v = fmaxf(v, __shfl_xor(v, off, 64));
      float mn = fmaxf(m_run[r], v);
      alpha[r] = __expf(m_run[r] - mn);
      m_run[r] = mn;
    }
#pragma unroll
    for (int r = 0; r < 4; ++r) {
      float s0 = 0.f;
#pragma unroll
      for (int c = 0; c < 4; ++c) {
        float p = __expf(sv[c][r] - m_run[r]);
        sv[c][r] = p; s0 += p;
      }
      l_run[r] = l_run[r]*alpha[r] + s0;   // per-lane; reduce at end
    }
#pragma unroll
    for (int dc = 0; dc < 4; ++dc) {
      f32x4 t = o_acc[dc];
#pragma unroll
      for (int r = 0; r < 4; ++r) t[r] *= alpha[r];
      o_acc[dc] = t;
    }
    // P round-trip (stride 72, 2-way free)
    h16* pw = bdw;
#pragma unroll
    for (int c = 0; c < 4; ++c)
#pragma unroll
      for (int r = 0; r < 4; ++r)
        pw[(quad*4 + r)*72 + c*16 + t16] = (h16)sv[c][r];

    h16x8 ap0 = *reinterpret_cast<const h16x8*>(pw + t16*72 + quad*8);
    h16x8 ap1 = *reinterpret_cast<const h16x8*>(pw + t16*72 + 32 + quad*8);
#pragma unroll
    for (int dc = 0; dc < 4; ++dc) {
      h16x8 bv0 = *reinterpret_cast<const h16x8*>(vt_sm + (dc*16 + t16)*64 + xg0);
      h16x8 bv1 = *reinterpret_cast<const h16x8*>(vt_sm + (dc*16 + t16)*64 + xg1);
      o_acc[dc] = mfma16(ap0, bv0, o_acc[dc]);
      o_acc[dc] = mfma16(ap1, bv1, o_acc[dc]);
    }
  }

  // finalize: reduce l across the quad's 16 lanes, write normalized h16 output
  const int b = bh >> 4, hh = bh & 15;
#pragma unroll
  for (int r = 0; r < 4; ++r) {
    float l = l_run[r];
#pragma unroll
    for (int off = 1; off < 16; off <<= 1) l += __shfl_xor(l, off, 64);
    float inv = 1.f / l;
    int i = iw + quad*4 + r;
    h16* dst = attn_h + ((size_t)(i*2 + b))*1024 + hh*64;
#pragma unroll
    for (int dc = 0; dc < 4; ++dc)
      dst[dc*16 + t16] = (h16)(o_acc[dc][r] * inv);
  }
}

extern "C" void kernel_launch(void* const* d_in, const int* in_sizes, int n_in,
                              void* d_out, int out_size, void* d_ws, size_t ws_size,
                              hipStream_t stream)
{
  const float* input  = (const float*)d_in[0];
  const float* pos    = (const float*)d_in[1];
  const float* fac    = (const float*)d_in[2];
  const float* w_in   = (const float*)d_in[3];
  const float* w_pos  = (const float*)d_in[4];
  const float* w_out  = (const float*)d_in[5];
  const float* bin_w  = (const float*)d_in[6];
  const float* bpos_w = (const float*)d_in[7];
  const float* bout_w = (const float*)d_in[8];
  const float* rw_w   = (const float*)d_in[9];
  const float* rr_w   = (const float*)d_in[10];
  float* out = (float*)d_out;
  (void)in_sizes; (void)n_in; (void)out_size; (void)ws_size;

  char* w = (char*)d_ws;
  auto take = [&](size_t bytes) { char* p = w; w += bytes; return p; };
  h16*   Win    = (h16*)take(3145728ull*2);
  h16*   Wpos   = (h16*)take(1048576ull*2);
  h16*   Wout   = (h16*)take(1048576ull*2);
  float* bin    = (float*)take(3072*4);
  float* bpos   = (float*)take(1024*4);
  float* bout   = (float*)take(1024*4);
  float* rw     = (float*)take(1024*4);
  float* rr     = (float*)take(1024*4);
  h16*   in_h   = (h16*)take(2097152ull*2);
  h16*   pos_h  = (h16*)take(4192256ull*2);   // OOB-read pad: buffers follow
  h16*   qrwb   = (h16*)take(2097152ull*2);
  h16*   qrrb   = (h16*)take(2097152ull*2);
  h16*   kb     = (h16*)take(2097152ull*2);
  h16*   vb     = (h16*)take(2097152ull*2);
  h16*   vbt    = (h16*)take(2097152ull*2);
  h16*   rb     = (h16*)take(4194304ull*2);
  h16*   attn_h = (h16*)take(2097152ull*2);

  // weights: 5120 blocks (256 rows/wave); tail: 7168 bias + 2048 rb + 262144 in
  // + 524032 pos = 795392 threads = 3107 blocks -> 8227 total
  hypernet_kernel<<<8227, 256, 0, stream>>>(fac, w_in, w_pos, w_out, bin_w, bpos_w, bout_w,
                                            rw_w, rr_w, Win, Wpos, Wout, bin, bpos, bout,
                                            rw, rr, rb, input, in_h, pos, pos_h);
  // merged qkv + pos GEMM: 384 + 256 = 640 blocks
  gemm01_kernel<<<640, 256, 0, stream>>>(in_h, Win, bin, pos_h, Wpos, bpos,
                                         rw, rr, qrwb, qrrb, kb, vb, rb);
  transpose_v_kernel<<<dim3(16, 32), 256, 0, stream>>>(vb, vbt);
  // flash: QBLK=128 -> grid (8, 32), 512 threads
  flash_kernel<<<dim3(8, 32), 512, 0, stream>>>(qrwb, qrrb, kb, vbt, rb, attn_h);
  // out GEMM: 64x128 tiles -> 256 blocks (1/CU)
  gemm2_kernel<<<dim3(8, 32), 256, 0, stream>>>(attn_h, Wout, bout, out);
}

// Round 9
// 345.599 us; speedup vs baseline: 1.0130x; 1.0130x over previous
//
#include <hip/hip_runtime.h>

// MPRelativeSelfMultiheadAttn on gfx950.  [R7-best configuration, 348.0 us]
// hypernet+casts (fused, coalesced weight dot8) -> merged fp16 MFMA GEMM
// (qkv + pos in ONE 640-block launch, XCD-chunked swizzle; global_load_lds
// with XOR-swizzled gather => conflict-free ds_read_b128) -> V transpose ->
// NO-SPLIT flash attention (QBLK=64, 4 waves; all 16 KV tiles per block,
// rel_shift fused, online softmax, writes attn_h h16 directly) ->
// out GEMM (64x128 tiles, 256 blocks = 1/CU).
// XOR swizzle: LDS(row, g) = global(row, g ^ (row&7)), granule = 16B.
// Fragment read granule = (kc*4+quad) ^ (t16&7): all 32 banks per 8-lane group.
//
// Session notes (falsified theories, do not retry):
//  - hypernet ILP/TLP/coalescing/sched_barrier: all null; plateau ~74us @20% HBM.
//  - flash QBLK=128 (halved staging): null-to-negative (barrier-path-bound).
//  - NT loads on weights: null (L3 residency unaffected, FETCH unchanged).

typedef _Float16 h16;
typedef _Float16 h16x8 __attribute__((ext_vector_type(8)));
typedef _Float16 h16x4 __attribute__((ext_vector_type(4)));
typedef float f32x4 __attribute__((ext_vector_type(4)));

static __device__ __forceinline__ f32x4 mfma16(h16x8 a, h16x8 b, f32x4 c) {
  return __builtin_amdgcn_mfma_f32_16x16x32_f16(a, b, c, 0, 0, 0);
}
static __device__ __forceinline__ void gload16(const void* g, void* l) {
  __builtin_amdgcn_global_load_lds((const __attribute__((address_space(1))) void*)g,
                                   (__attribute__((address_space(3))) void*)l, 16, 0, 0);
}

// ---------------- hypernet + casts (fused, coalesced weight path) ----------------
__global__ __launch_bounds__(256) void hypernet_kernel(
    const float* __restrict__ fac,
    const float* __restrict__ w_in, const float* __restrict__ w_pos,
    const float* __restrict__ w_out, const float* __restrict__ b_in_w,
    const float* __restrict__ b_pos_w, const float* __restrict__ b_out_w,
    const float* __restrict__ rw_w, const float* __restrict__ rr_w,
    h16* __restrict__ Win, h16* __restrict__ Wpos, h16* __restrict__ Wout,
    float* __restrict__ bin, float* __restrict__ bpos, float* __restrict__ bout,
    float* __restrict__ rw, float* __restrict__ rr, h16* __restrict__ rb,
    const float* __restrict__ input, h16* __restrict__ in_h,
    const float* __restrict__ pos, h16* __restrict__ pos_h)
{
  float f0=fac[0],f1=fac[1],f2=fac[2],f3=fac[3],f4=fac[4],f5=fac[5],f6=fac[6],f7=fac[7];
#define DOT8(p) ((p)[0]*f0+(p)[1]*f1+(p)[2]*f2+(p)[3]*f3+(p)[4]*f4+(p)[5]*f5+(p)[6]*f6+(p)[7]*f7)
  // ---- weight path: blocks [0, 5120), 256 rows per wave ----
  if (blockIdx.x < 5120) {
    const int lane = threadIdx.x & 63;
    const int gw = blockIdx.x * 4 + (threadIdx.x >> 6);   // global wave id
    size_t rowBase = (size_t)gw * 256;
    const float* srcp; h16* dstp; size_t lr;
    if (rowBase < 3145728)      { srcp = w_in;  dstp = Win;  lr = rowBase; }
    else if (rowBase < 4194304) { srcp = w_pos; dstp = Wpos; lr = rowBase - 3145728; }
    else                        { srcp = w_out; dstp = Wout; lr = rowBase - 4194304; }
    const f32x4* p = reinterpret_cast<const f32x4*>(srcp) + lr*2;
    const int pi = (lane < 32) ? (lane << 1) : (((lane - 32) << 1) | 1);
    const float fa = (lane < 32) ? f0 : f4;
    const float fb = (lane < 32) ? f1 : f5;
    const float fc = (lane < 32) ? f2 : f6;
    const float fd = (lane < 32) ? f3 : f7;
    f32x4 v[8];
#pragma unroll
    for (int u = 0; u < 8; ++u) v[u] = p[(size_t)u*64 + pi];   // coalesced 1KB each
    float full[8];
#pragma unroll
    for (int u = 0; u < 8; ++u) {
      float part = v[u].x*fa + v[u].y*fb + v[u].z*fc + v[u].w*fd;
      full[u] = part + __shfl_xor(part, 32, 64);
    }
    if (lane < 32) {
#pragma unroll
      for (int u = 0; u < 8; ++u)
        dstp[lr + u*32 + lane] = (h16)full[u];
    }
    return;
  }
  int idx = (blockIdx.x - 5120) * 256 + threadIdx.x;
  // ---- tiny sections (1 output per thread) ----
  if (idx < 3072) { bin[idx]  = DOT8(b_in_w  + (size_t)idx*8); return; }
  idx -= 3072;
  if (idx < 1024) { bpos[idx] = DOT8(b_pos_w + (size_t)idx*8); return; }
  idx -= 1024;
  if (idx < 1024) { bout[idx] = DOT8(b_out_w + (size_t)idx*8); return; }
  idx -= 1024;
  if (idx < 1024) { rw[idx]   = DOT8(rw_w    + (size_t)idx*8); return; }
  idx -= 1024;
  if (idx < 1024) { rr[idx]   = DOT8(rr_w    + (size_t)idx*8); return; }
  idx -= 1024;
  if (idx < 2048) { rb[(((size_t)(idx >> 6)) << 17) + 2047*64 + (idx & 63)] = (h16)0.f; return; }
  idx -= 2048;
  // ---- casts: 2 float4 per thread -> one h16x8 store ----
  if (idx < 262144) {   // input: 524288 float4 total
    const float4* ip = reinterpret_cast<const float4*>(input) + (size_t)idx*2;
    float4 a = ip[0], b = ip[1];
    h16x8 o = { (h16)a.x, (h16)a.y, (h16)a.z, (h16)a.w,
                (h16)b.x, (h16)b.y, (h16)b.z, (h16)b.w };
    reinterpret_cast<h16x8*>(in_h)[idx] = o;
    return;
  }
  idx -= 262144;
  if (idx < 524032) {   // pos: 1048064 float4 total
    const float4* pp = reinterpret_cast<const float4*>(pos) + (size_t)idx*2;
    float4 a = pp[0], b = pp[1];
    h16x8 o = { (h16)a.x, (h16)a.y, (h16)a.z, (h16)a.w,
                (h16)b.x, (h16)b.y, (h16)b.z, (h16)b.w };
    reinterpret_cast<h16x8*>(pos_h)[idx] = o;
  }
#undef DOT8
}

// ---------------- merged GEMM: mode0 qkv (24x16) + mode1 pos (8x32), 640 blocks ----------------
__global__ __launch_bounds__(256) void gemm01_kernel(
    const h16* __restrict__ A0, const h16* __restrict__ B0, const float* __restrict__ bias0,
    const h16* __restrict__ A1, const h16* __restrict__ B1, const float* __restrict__ bias1,
    const float* __restrict__ rwv, const float* __restrict__ rrv,
    h16* __restrict__ o0, h16* __restrict__ o1,
    h16* __restrict__ o2, h16* __restrict__ o3, h16* __restrict__ r_out)
{
  __shared__ __align__(16) h16 a_sm[128*64];
  __shared__ __align__(16) h16 b_sm[128*64];
  // XCD swizzle: 80 consecutive logical blocks per XCD
  const int bx = blockIdx.x;
  const int swz = (bx & 7) * 80 + (bx >> 3);
  int mode, bxx, byy;
  if (swz < 384) { mode = 0; bxx = swz % 24; byy = swz / 24; }
  else           { mode = 1; int b = swz - 384; bxx = b & 7; byy = b >> 3; }
  const h16* __restrict__ A  = mode ? A1 : A0;
  const h16* __restrict__ Bw = mode ? B1 : B0;
  const float* __restrict__ bias = mode ? bias1 : bias0;
  const int M = mode ? 4094 : 2048;
  const int K = 1024;

  const int tid = threadIdx.x, lane = tid & 63, wave = tid >> 6;
  const int quad = lane >> 4, t16 = lane & 15;
  const int wm = wave >> 1, wn = wave & 1;
  const int m0 = byy * 128, n0 = bxx * 128;
  const int lrow = lane >> 3, lgran = lane & 7;
  const int gsw = (lgran ^ lrow) * 8;          // swizzled source col offset (h16)
  const int xg0 = (quad ^ (t16 & 7)) * 8;      // fragment granule, kc=0
  const int xg1 = xg0 ^ 32;                    // kc=1

  f32x4 acc[4][4];
#pragma unroll
  for (int i = 0; i < 4; ++i)
#pragma unroll
    for (int j = 0; j < 4; ++j) acc[i][j] = (f32x4){0.f,0.f,0.f,0.f};

  for (int k0 = 0; k0 < K; k0 += 64) {
    __syncthreads();
#pragma unroll
    for (int s = 0; s < 4; ++s) {
      int rbase = wave*32 + s*8;
      gload16(A  + (size_t)(m0 + rbase + lrow)*K + k0 + gsw, a_sm + rbase*64);
      gload16(Bw + (size_t)(n0 + rbase + lrow)*K + k0 + gsw, b_sm + rbase*64);
    }
    __syncthreads();
#pragma unroll
    for (int kc = 0; kc < 2; ++kc) {
      const int xg = kc ? xg1 : xg0;
      h16x8 af[4], bfr[4];
#pragma unroll
      for (int i = 0; i < 4; ++i) {
        af[i]  = *reinterpret_cast<const h16x8*>(a_sm + (wm*64 + i*16 + t16)*64 + xg);
        bfr[i] = *reinterpret_cast<const h16x8*>(b_sm + (wn*64 + i*16 + t16)*64 + xg);
      }
#pragma unroll
      for (int i = 0; i < 4; ++i)
#pragma unroll
        for (int j = 0; j < 4; ++j)
          acc[i][j] = mfma16(af[i], bfr[j], acc[i][j]);
    }
  }

  // epilogue: C/D layout row=(lane>>4)*4+reg, col=lane&15
#pragma unroll
  for (int i = 0; i < 4; ++i) {
    int mb = m0 + wm*64 + i*16 + quad*4;
#pragma unroll
    for (int j = 0; j < 4; ++j) {
      int n = n0 + wn*64 + j*16 + t16;
      float bv = bias[n];
      if (mode == 0) {
        int nn = n & 1023, sec = n >> 10, hh = nn >> 6, d = nn & 63;
        float rwb = rwv[nn], rrb = rrv[nn];
#pragma unroll
        for (int r = 0; r < 4; ++r) {
          int m = mb + r, t = m >> 1, b = m & 1;
          size_t off = ((size_t)((b << 4) + hh) << 16) + (t << 6) + d;
          float v = acc[i][j][r] + bv;
          if (sec == 0)      { o0[off] = (h16)(v + rwb); o1[off] = (h16)(v + rrb); }
          else if (sec == 1) { o2[off] = (h16)v; }
          else               { o3[off] = (h16)v; }
        }
      } else {
        int hh = n >> 6, d = n & 63;
#pragma unroll
        for (int r = 0; r < 4; ++r) {
          int m = mb + r;
          if (m < M) {
            int rel = m >> 1, b = m & 1;
            r_out[(((size_t)((b << 4) + hh)) << 17) + (rel << 6) + d] = (h16)(acc[i][j][r] + bv);
          }
        }
      }
    }
  }
}

// ---------------- out GEMM: 64x128 tiles, 256 blocks (1/CU) ----------------
__global__ __launch_bounds__(256) void gemm2_kernel(
    const h16* __restrict__ A, const h16* __restrict__ Bw,
    const float* __restrict__ bias, float* __restrict__ Cout)
{
  __shared__ __align__(16) h16 a_sm[64*64];
  __shared__ __align__(16) h16 b_sm[128*64];
  const int tid = threadIdx.x, lane = tid & 63, wave = tid >> 6;
  const int quad = lane >> 4, t16 = lane & 15;
  const int wm = wave >> 1, wn = wave & 1;
  const int m0 = blockIdx.y * 64, n0 = blockIdx.x * 128;
  const int lrow = lane >> 3, lgran = lane & 7;
  const int gsw = (lgran ^ lrow) * 8;
  const int xg0 = (quad ^ (t16 & 7)) * 8;
  const int xg1 = xg0 ^ 32;
  const int K = 1024, N = 1024;

  f32x4 acc[2][4];
#pragma unroll
  for (int i = 0; i < 2; ++i)
#pragma unroll
    for (int j = 0; j < 4; ++j) acc[i][j] = (f32x4){0.f,0.f,0.f,0.f};

  for (int k0 = 0; k0 < K; k0 += 64) {
    __syncthreads();
#pragma unroll
    for (int s = 0; s < 2; ++s) {   // A: 64 rows, 16/wave
      int rbase = wave*16 + s*8;
      gload16(A + (size_t)(m0 + rbase + lrow)*K + k0 + gsw, a_sm + rbase*64);
    }
#pragma unroll
    for (int s = 0; s < 4; ++s) {   // B: 128 rows, 32/wave
      int rbase = wave*32 + s*8;
      gload16(Bw + (size_t)(n0 + rbase + lrow)*K + k0 + gsw, b_sm + rbase*64);
    }
    __syncthreads();
#pragma unroll
    for (int kc = 0; kc < 2; ++kc) {
      const int xg = kc ? xg1 : xg0;
      h16x8 af[2], bfr[4];
#pragma unroll
      for (int i = 0; i < 2; ++i)
        af[i]  = *reinterpret_cast<const h16x8*>(a_sm + (wm*32 + i*16 + t16)*64 + xg);
#pragma unroll
      for (int j = 0; j < 4; ++j)
        bfr[j] = *reinterpret_cast<const h16x8*>(b_sm + (wn*64 + j*16 + t16)*64 + xg);
#pragma unroll
      for (int i = 0; i < 2; ++i)
#pragma unroll
        for (int j = 0; j < 4; ++j)
          acc[i][j] = mfma16(af[i], bfr[j], acc[i][j]);
    }
  }

#pragma unroll
  for (int i = 0; i < 2; ++i) {
    int mb = m0 + wm*32 + i*16 + quad*4;
#pragma unroll
    for (int j = 0; j < 4; ++j) {
      int n = n0 + wn*64 + j*16 + t16;
      float bv = bias[n];
#pragma unroll
      for (int r = 0; r < 4; ++r)
        Cout[(size_t)(mb + r)*N + n] = acc[i][j][r] + bv;
    }
  }
}

// ---------------- V transpose: vb [BH][T][64] -> vbt [BH][64][T] ----------------
__global__ __launch_bounds__(256) void transpose_v_kernel(
    const h16* __restrict__ vb, h16* __restrict__ vbt)
{
  __shared__ h16 tile[64*72];
  const int bh = blockIdx.y, t0 = blockIdx.x * 64;
  const int r = threadIdx.x >> 3, c = (threadIdx.x & 7) * 8;
  const h16* src = vb + ((size_t)bh << 16) + (size_t)(t0 + r)*64 + c;
  *reinterpret_cast<h16x8*>(tile + r*72 + c)        = *reinterpret_cast<const h16x8*>(src);
  *reinterpret_cast<h16x8*>(tile + (r + 32)*72 + c) = *reinterpret_cast<const h16x8*>(src + 32*64);
  __syncthreads();
  h16x8 o0, o1;
#pragma unroll
  for (int e = 0; e < 8; ++e) {
    o0[e] = tile[(c + e)*72 + r];
    o1[e] = tile[(c + e)*72 + r + 32];
  }
  h16* dst = vbt + ((size_t)bh << 16) + (size_t)r*1024 + t0 + c;
  *reinterpret_cast<h16x8*>(dst)            = o0;
  *reinterpret_cast<h16x8*>(dst + 32*1024)  = o1;
}

// ---------------- flash attention, QBLK=64 (4 waves), writes attn_h directly ----------------
__global__ __launch_bounds__(256) void flash_kernel(
    const h16* __restrict__ qrw, const h16* __restrict__ qrr,
    const h16* __restrict__ kb, const h16* __restrict__ vbt,
    const h16* __restrict__ rb,
    h16* __restrict__ attn_h)
{
  __shared__ __align__(16) h16 k_sm[64*64];
  __shared__ __align__(16) h16 vt_sm[64*64];
  __shared__ __align__(16) h16 r_sm[128*64];   // reused as BD/P spill after barrier

  const int tid = threadIdx.x, lane = tid & 63, wave = tid >> 6;
  const int quad = lane >> 4, t16 = lane & 15;
  const int bh = blockIdx.y, i0 = blockIdx.x * 64;
  const size_t base  = (size_t)bh << 16;
  const size_t rbase = (size_t)bh << 17;
  const int iw = i0 + wave * 16;
  const int lrow = lane >> 3, lgran = lane & 7;
  const int gsw = (lgran ^ lrow) * 8;
  const int xg0 = (quad ^ (t16 & 7)) * 8;
  const int xg1 = xg0 ^ 32;

  h16x8 a_rw[2], a_rr[2];
  {
    const h16* p = qrw + base + (size_t)(iw + t16)*64 + quad*8;
    a_rw[0] = *reinterpret_cast<const h16x8*>(p);
    a_rw[1] = *reinterpret_cast<const h16x8*>(p + 32);
    const h16* p2 = qrr + base + (size_t)(iw + t16)*64 + quad*8;
    a_rr[0] = *reinterpret_cast<const h16x8*>(p2);
    a_rr[1] = *reinterpret_cast<const h16x8*>(p2 + 32);
  }

  f32x4 o_acc[4];
#pragma unroll
  for (int dc = 0; dc < 4; ++dc) o_acc[dc] = (f32x4){0.f,0.f,0.f,0.f};
  float m_run[4] = {-1e30f,-1e30f,-1e30f,-1e30f};
  float l_run[4] = {0.f,0.f,0.f,0.f};   // per-lane partial; reduced at end

  h16* bdw = r_sm + wave * (16*84);
  const int cb0 = 3 - wave;

  for (int j0 = 0; j0 < 1024; j0 += 64) {
    __syncthreads();
    { // swizzled staging
#pragma unroll
      for (int s = 0; s < 2; ++s) {
        int row = wave*16 + s*8;
        gload16(kb  + base + (size_t)(j0 + row + lrow)*64 + gsw, k_sm  + row*64);
        gload16(vbt + base + (size_t)(row + lrow)*1024 + j0 + gsw, vt_sm + row*64);
      }
      const int rel0 = j0 - i0 + 960;
#pragma unroll
      for (int s = 0; s < 4; ++s) {
        int row = wave*32 + s*8;
        gload16(rb + rbase + (size_t)(rel0 + row + lrow)*64 + gsw, r_sm + row*64);
      }
    }
    __syncthreads();

    f32x4 s_ac[4];
#pragma unroll
    for (int c = 0; c < 4; ++c) {
      s_ac[c] = (f32x4){0.f,0.f,0.f,0.f};
      s_ac[c] = mfma16(a_rw[0], *reinterpret_cast<const h16x8*>(k_sm + (c*16 + t16)*64 + xg0), s_ac[c]);
      s_ac[c] = mfma16(a_rw[1], *reinterpret_cast<const h16x8*>(k_sm + (c*16 + t16)*64 + xg1), s_ac[c]);
    }
    f32x4 s_bd[5];
#pragma unroll
    for (int u = 0; u < 5; ++u) {
      s_bd[u] = (f32x4){0.f,0.f,0.f,0.f};
      s_bd[u] = mfma16(a_rr[0], *reinterpret_cast<const h16x8*>(r_sm + ((cb0+u)*16 + t16)*64 + xg0), s_bd[u]);
      s_bd[u] = mfma16(a_rr[1], *reinterpret_cast<const h16x8*>(r_sm + ((cb0+u)*16 + t16)*64 + xg1), s_bd[u]);
    }
    __syncthreads();  // r_sm reads done before spilling into it

    // BD spill (C-layout), stride 84
#pragma unroll
    for (int u = 0; u < 5; ++u)
#pragma unroll
      for (int r = 0; r < 4; ++r)
        bdw[(quad*4 + r)*84 + u*16 + t16] = (h16)s_bd[u][r];

    // combine with relative shift
    float sv[4][4];
#pragma unroll
    for (int c = 0; c < 4; ++c)
#pragma unroll
      for (int r = 0; r < 4; ++r) {
        int il = quad*4 + r;
        float bdv = (float)bdw[il*84 + c*16 + t16 + 15 - il];
        sv[c][r] = (s_ac[c][r] + bdv) * 0.125f;
      }

    // online softmax: shared row max (shfl), per-lane l partial
    float alpha[4];
#pragma unroll
    for (int r = 0; r < 4; ++r) {
      float v = fmaxf(fmaxf(sv[0][r], sv[1][r]), fmaxf(sv[2][r], sv[3][r]));
#pragma unroll
      for (int off = 1; off < 16; off <<= 1) v = fmaxf(v, __shfl_xor(v, off, 64));
      float mn = fmaxf(m_run[r], v);
      alpha[r] = __expf(m_run[r] - mn);
      m_run[r] = mn;
    }
#pragma unroll
    for (int r = 0; r < 4; ++r) {
      float s0 = 0.f;
#pragma unroll
      for (int c = 0; c < 4; ++c) {
        float p = __expf(sv[c][r] - m_run[r]);
        sv[c][r] = p; s0 += p;
      }
      l_run[r] = l_run[r]*alpha[r] + s0;   // per-lane; reduce at end
    }
#pragma unroll
    for (int dc = 0; dc < 4; ++dc) {
      f32x4 t = o_acc[dc];
#pragma unroll
      for (int r = 0; r < 4; ++r) t[r] *= alpha[r];
      o_acc[dc] = t;
    }
    // P round-trip (stride 72, 2-way free)
    h16* pw = bdw;
#pragma unroll
    for (int c = 0; c < 4; ++c)
#pragma unroll
      for (int r = 0; r < 4; ++r)
        pw[(quad*4 + r)*72 + c*16 + t16] = (h16)sv[c][r];

    h16x8 ap0 = *reinterpret_cast<const h16x8*>(pw + t16*72 + quad*8);
    h16x8 ap1 = *reinterpret_cast<const h16x8*>(pw + t16*72 + 32 + quad*8);
#pragma unroll
    for (int dc = 0; dc < 4; ++dc) {
      h16x8 bv0 = *reinterpret_cast<const h16x8*>(vt_sm + (dc*16 + t16)*64 + xg0);
      h16x8 bv1 = *reinterpret_cast<const h16x8*>(vt_sm + (dc*16 + t16)*64 + xg1);
      o_acc[dc] = mfma16(ap0, bv0, o_acc[dc]);
      o_acc[dc] = mfma16(ap1, bv1, o_acc[dc]);
    }
  }

  // finalize: reduce l across the quad's 16 lanes, write normalized h16 output
  const int b = bh >> 4, hh = bh & 15;
#pragma unroll
  for (int r = 0; r < 4; ++r) {
    float l = l_run[r];
#pragma unroll
    for (int off = 1; off < 16; off <<= 1) l += __shfl_xor(l, off, 64);
    float inv = 1.f / l;
    int i = iw + quad*4 + r;
    h16* dst = attn_h + ((size_t)(i*2 + b))*1024 + hh*64;
#pragma unroll
    for (int dc = 0; dc < 4; ++dc)
      dst[dc*16 + t16] = (h16)(o_acc[dc][r] * inv);
  }
}

extern "C" void kernel_launch(void* const* d_in, const int* in_sizes, int n_in,
                              void* d_out, int out_size, void* d_ws, size_t ws_size,
                              hipStream_t stream)
{
  const float* input  = (const float*)d_in[0];
  const float* pos    = (const float*)d_in[1];
  const float* fac    = (const float*)d_in[2];
  const float* w_in   = (const float*)d_in[3];
  const float* w_pos  = (const float*)d_in[4];
  const float* w_out  = (const float*)d_in[5];
  const float* bin_w  = (const float*)d_in[6];
  const float* bpos_w = (const float*)d_in[7];
  const float* bout_w = (const float*)d_in[8];
  const float* rw_w   = (const float*)d_in[9];
  const float* rr_w   = (const float*)d_in[10];
  float* out = (float*)d_out;
  (void)in_sizes; (void)n_in; (void)out_size; (void)ws_size;

  char* w = (char*)d_ws;
  auto take = [&](size_t bytes) { char* p = w; w += bytes; return p; };
  h16*   Win    = (h16*)take(3145728ull*2);
  h16*   Wpos   = (h16*)take(1048576ull*2);
  h16*   Wout   = (h16*)take(1048576ull*2);
  float* bin    = (float*)take(3072*4);
  float* bpos   = (float*)take(1024*4);
  float* bout   = (float*)take(1024*4);
  float* rw     = (float*)take(1024*4);
  float* rr     = (float*)take(1024*4);
  h16*   in_h   = (h16*)take(2097152ull*2);
  h16*   pos_h  = (h16*)take(4192256ull*2);   // OOB-read pad: buffers follow
  h16*   qrwb   = (h16*)take(2097152ull*2);
  h16*   qrrb   = (h16*)take(2097152ull*2);
  h16*   kb     = (h16*)take(2097152ull*2);
  h16*   vb     = (h16*)take(2097152ull*2);
  h16*   vbt    = (h16*)take(2097152ull*2);
  h16*   rb     = (h16*)take(4194304ull*2);
  h16*   attn_h = (h16*)take(2097152ull*2);

  // weights: 5120 blocks (256 rows/wave); tail: 7168 bias + 2048 rb + 262144 in
  // + 524032 pos = 795392 threads = 3107 blocks -> 8227 total
  hypernet_kernel<<<8227, 256, 0, stream>>>(fac, w_in, w_pos, w_out, bin_w, bpos_w, bout_w,
                                            rw_w, rr_w, Win, Wpos, Wout, bin, bpos, bout,
                                            rw, rr, rb, input, in_h, pos, pos_h);
  // merged qkv + pos GEMM: 384 + 256 = 640 blocks
  gemm01_kernel<<<640, 256, 0, stream>>>(in_h, Win, bin, pos_h, Wpos, bpos,
                                         rw, rr, qrwb, qrrb, kb, vb, rb);
  transpose_v_kernel<<<dim3(16, 32), 256, 0, stream>>>(vb, vbt);
  flash_kernel<<<dim3(16, 32), 256, 0, stream>>>(qrwb, qrrb, kb, vbt, rb, attn_h);
  // out GEMM: 64x128 tiles -> 256 blocks (1/CU)
  gemm2_kernel<<<dim3(8, 32), 256, 0, stream>>>(attn_h, Wout, bout, out);
}